// Round 10
// baseline (57.097 us; speedup 1.0000x reference)
//
#include <hip/hip_runtime.h>
#include <stdint.h>

#define NBITS 57
#define RPB   256

__global__ __launch_bounds__(256) void lzc57_kernel(const uint32_t* __restrict__ X,
                                                    float* __restrict__ out,
                                                    int nrows) {
    __shared__ __align__(16) float s_out[RPB * 6];   // 6144 B (output coalescing only)
    const int tid  = threadIdx.x;
    const int row0 = blockIdx.x * RPB;
    const int row  = row0 + tid;
    const int rows = min(RPB, nrows - row0);

    if (row < nrows) {
        const size_t w0   = (size_t)row * NBITS;     // row's first word index
        const size_t sw   = w0 & ~(size_t)15;        // 64B sector base (words)
        const int    start = (int)(w0 - sw);         // 0..15
        const uint4* p = (const uint4*)(X + sw);

        // hot load: exactly ONE 64B sector
        uint4 d[4];
        #pragma unroll
        for (int i = 0; i < 4; ++i) d[i] = p[i];

        uint32_t w[16];
        #pragma unroll
        for (int i = 0; i < 4; ++i) {
            w[4*i+0] = d[i].x; w[4*i+1] = d[i].y;
            w[4*i+2] = d[i].z; w[4*i+3] = d[i].w;
        }
        // words are exactly 0x3F800000 (1.0f) or 0: bit 29 discriminates
        uint32_t mA = 0u;
        #pragma unroll
        for (int k = 0; k < 16; ++k)
            mA |= ((w[k] >> 29) & 1u) << k;

        uint32_t vm = mA >> start;          // bit j = row word j (16-start valid bits)

        if (start >= 14) {
            // head too close to sector end (would check <=2 words): pull next sector too
            uint4 e[4];
            #pragma unroll
            for (int i = 0; i < 4; ++i) e[i] = p[4 + i];
            uint32_t w2[16];
            #pragma unroll
            for (int i = 0; i < 4; ++i) {
                w2[4*i+0] = e[i].x; w2[4*i+1] = e[i].y;
                w2[4*i+2] = e[i].z; w2[4*i+3] = e[i].w;
            }
            uint32_t mB = 0u;
            #pragma unroll
            for (int k = 0; k < 16; ++k)
                mB |= ((w2[k] >> 29) & 1u) << k;
            vm = (mA | (mB << 16)) >> start;   // 32-start = 17..18 valid bits
        }

        int lzc;
        if (vm) {
            lzc = __ffs(vm) - 1;               // hot path
        } else {
            // cold path (~1.6% of rows): full 57-word scalar scan
            const uint32_t* rw = X + w0;
            uint32_t mlo = 0u, mhi = 0u;
            #pragma unroll
            for (int i = 0; i < 32; ++i)
                mlo |= ((rw[i] >> 29) & 1u) << i;
            #pragma unroll
            for (int i = 32; i < NBITS; ++i)
                mhi |= ((rw[i] >> 29) & 1u) << (i - 32);
            lzc = mlo ? (__ffs(mlo) - 1) : (mhi ? (31 + __ffs(mhi)) : NBITS);
        }

        #pragma unroll
        for (int j = 0; j < 6; ++j)
            s_out[tid * 6 + j] = (float)((lzc >> (5 - j)) & 1);
    }
    __syncthreads();

    // ---- coalesced float4 store of staged output ----
    float* dstf = out + (size_t)row0 * 6;
    const int nout = rows * 6;
    const int no4 = nout >> 2;
    const float4* s4 = (const float4*)s_out;
    float4* o4 = (float4*)dstf;
    for (int i = tid; i < no4; i += RPB) o4[i] = s4[i];
    for (int i = (no4 << 2) + tid; i < nout; i += RPB) dstf[i] = s_out[i];
}

extern "C" void kernel_launch(void* const* d_in, const int* in_sizes, int n_in,
                              void* d_out, int out_size, void* d_ws, size_t ws_size,
                              hipStream_t stream) {
    const uint32_t* X = (const uint32_t*)d_in[0];
    float* out = (float*)d_out;
    const int nrows = in_sizes[0] / NBITS;
    const int blocks = (nrows + RPB - 1) / RPB;
    lzc57_kernel<<<blocks, RPB, 0, stream>>>(X, out, nrows);
}

// Round 11
// 51.671 us; speedup vs baseline: 1.1050x; 1.1050x over previous
//
#include <hip/hip_runtime.h>
#include <stdint.h>

#define NBITS 57
#define RPB   256

__global__ __launch_bounds__(256) void lzc57_kernel(const uint32_t* __restrict__ X,
                                                    float* __restrict__ out,
                                                    int nrows) {
    __shared__ __align__(16) float s_out[RPB * 6];   // 6144 B (output coalescing only)
    const int tid  = threadIdx.x;
    const int row0 = blockIdx.x * RPB;
    const int row  = row0 + tid;
    const int rows = min(RPB, nrows - row0);

    if (row < nrows) {
        const size_t w0 = (size_t)row * NBITS;        // row's first word index
        const size_t lw = w0 & ~(size_t)31;           // 128B line base (words)
        const int off   = (int)(w0 - lw);             // 0..31
        // 64B window clamped to stay inside this row's head 128B line:
        //   off<=19: 16B-aligned at w0  -> start=off&3, checks >=13 words
        //   off>=20: snapped to line+64 -> start=off-16, checks 32-off words
        const int wb_off = (off <= 19) ? (off & ~3) : 16;   // window base within line (words)
        const int start  = off - wb_off;                    // row word 0 position in window
        const uint4* p = (const uint4*)(X + lw + wb_off);

        uint4 d[4];
        #pragma unroll
        for (int i = 0; i < 4; ++i) d[i] = p[i];      // 4 dwordx4, all in ONE 128B line

        uint32_t w[16];
        #pragma unroll
        for (int i = 0; i < 4; ++i) {
            w[4*i+0] = d[i].x; w[4*i+1] = d[i].y;
            w[4*i+2] = d[i].z; w[4*i+3] = d[i].w;
        }
        // words are exactly 0x3F800000 (1.0f) or 0: bit 29 discriminates
        uint32_t m = 0u;
        #pragma unroll
        for (int k = 0; k < 16; ++k)
            m |= ((w[k] >> 29) & 1u) << k;
        const uint32_t vm = m >> start;   // bit j = row word j; prev-row bits shifted out

        int lzc;
        if (vm) {
            lzc = __ffs(vm) - 1;          // hot path: first 1 within the head line
        } else {
            // cold path (~3% of rows): full 57-word scalar scan
            const uint32_t* rw = X + w0;
            uint32_t mlo = 0u, mhi = 0u;
            #pragma unroll
            for (int i = 0; i < 32; ++i)
                mlo |= ((rw[i] >> 29) & 1u) << i;
            #pragma unroll
            for (int i = 32; i < NBITS; ++i)
                mhi |= ((rw[i] >> 29) & 1u) << (i - 32);
            lzc = mlo ? (__ffs(mlo) - 1) : (mhi ? (31 + __ffs(mhi)) : NBITS);
        }

        #pragma unroll
        for (int j = 0; j < 6; ++j)
            s_out[tid * 6 + j] = (float)((lzc >> (5 - j)) & 1);
    }
    __syncthreads();

    // ---- coalesced float4 store of staged output ----
    float* dstf = out + (size_t)row0 * 6;
    const int nout = rows * 6;
    const int no4 = nout >> 2;
    const float4* s4 = (const float4*)s_out;
    float4* o4 = (float4*)dstf;
    for (int i = tid; i < no4; i += RPB) o4[i] = s4[i];
    for (int i = (no4 << 2) + tid; i < nout; i += RPB) dstf[i] = s_out[i];
}

extern "C" void kernel_launch(void* const* d_in, const int* in_sizes, int n_in,
                              void* d_out, int out_size, void* d_ws, size_t ws_size,
                              hipStream_t stream) {
    const uint32_t* X = (const uint32_t*)d_in[0];
    float* out = (float*)d_out;
    const int nrows = in_sizes[0] / NBITS;
    const int blocks = (nrows + RPB - 1) / RPB;
    lzc57_kernel<<<blocks, RPB, 0, stream>>>(X, out, nrows);
}